// Round 11
// baseline (407.198 us; speedup 1.0000x reference)
//
#include <hip/hip_runtime.h>

#define HH 128
#define BN_EPS 1e-5f

typedef __attribute__((ext_vector_type(8))) short short8;
typedef __attribute__((ext_vector_type(4))) float floatx4;

__device__ inline short8 mk8(uint a, uint b, uint c, uint d) {
    union { uint u[4]; short8 s; } t;
    t.u[0] = a; t.u[1] = b; t.u[2] = c; t.u[3] = d;
    return t.s;
}

__device__ inline ushort f2bf(float f) {
    uint u = __float_as_uint(f);
    u = u + 0x7FFFu + ((u >> 16) & 1u);
    return (ushort)(u >> 16);
}

__device__ inline uint packbf(float lo, float hi) {
    return ((uint)f2bf(hi) << 16) | (uint)f2bf(lo);
}

__device__ inline float bfLo(uint u) { return __uint_as_float(u << 16); }
__device__ inline float bfHi(uint u) { return __uint_as_float(u & 0xFFFF0000u); }

__device__ inline void splitPair(float f0, float f1, uint& hw, uint& lw) {
    uint u0 = __float_as_uint(f0), u1 = __float_as_uint(f1);
    hw = __builtin_amdgcn_perm(u1, u0, 0x07060302);
    float r0 = f0 - __uint_as_float(u0 & 0xFFFF0000u);
    float r1 = f1 - __uint_as_float(u1 & 0xFFFF0000u);
    lw = __builtin_amdgcn_perm(__float_as_uint(r1), __float_as_uint(r0), 0x07060302);
}

// ================= CSR build via 2-level bucket sort (NO global atomics) ====
// bucket h = dst>>8 covers exactly nodes [h*256, h*256+256) -> bucket totals
// double as the rowptr block bases (scanA/scanB of old versions are redundant).

__global__ __launch_bounds__(256) void k_ahist(const int* __restrict__ dst,
                                               int* __restrict__ gH, int E, int tile) {
    __shared__ int hist[256];
    int b = blockIdx.x, tid = threadIdx.x;
    hist[tid] = 0;
    __syncthreads();
    int s0 = b * tile, s1 = min(s0 + tile, E);
    for (int i = s0 + tid; i < s1; i += 256)
        atomicAdd(&hist[((unsigned)dst[i]) >> 8], 1);
    __syncthreads();
    gH[tid * 256 + b] = hist[tid];
}

__global__ __launch_bounds__(256) void k_scan1(const int* __restrict__ gH,
                                               int* __restrict__ gC,
                                               int* __restrict__ totals) {
    __shared__ int s[256];
    int h = blockIdx.x, b = threadIdx.x;
    int v = gH[h * 256 + b];
    s[b] = v;
    __syncthreads();
    for (int off = 1; off < 256; off <<= 1) {
        int t = (b >= off) ? s[b - off] : 0;
        __syncthreads();
        s[b] += t;
        __syncthreads();
    }
    gC[h * 256 + b] = s[b] - v;
    if (b == 255) totals[h] = s[255];
}

__global__ __launch_bounds__(256) void k_scan2(const int* __restrict__ totals,
                                               int* __restrict__ base) {
    __shared__ int s[256];
    int tid = threadIdx.x;
    int v = totals[tid];
    s[tid] = v;
    __syncthreads();
    for (int off = 1; off < 256; off <<= 1) {
        int t = (tid >= off) ? s[tid - off] : 0;
        __syncthreads();
        s[tid] += t;
        __syncthreads();
    }
    base[tid] = s[tid] - v;
    if (tid == 255) base[256] = s[255];
}

__global__ __launch_bounds__(256) void k_asc(const int* __restrict__ src,
                                             const int* __restrict__ dst,
                                             const int* __restrict__ gC,
                                             const int* __restrict__ base,
                                             uint2* __restrict__ bucketed,
                                             int E, int tile) {
    __shared__ int cur[256];
    int b = blockIdx.x, tid = threadIdx.x;
    cur[tid] = gC[tid * 256 + b] + base[tid];
    __syncthreads();
    int s0 = b * tile, s1 = min(s0 + tile, E);
    for (int i = s0 + tid; i < s1; i += 256) {
        int d = dst[i];
        int pos = atomicAdd(&cur[((unsigned)d) >> 8], 1);
        bucketed[pos] = make_uint2((uint)src[i], (uint)d);
    }
}

// per-bucket low-byte histogram == degree; fused dinv
__global__ __launch_bounds__(256) void k_bdeg(const uint2* __restrict__ bucketed,
                                              const int* __restrict__ base,
                                              int* __restrict__ degInt,
                                              float* __restrict__ dinv, int N) {
    __shared__ int hist[256];
    int h = blockIdx.x, tid = threadIdx.x;
    hist[tid] = 0;
    __syncthreads();
    int s0 = base[h], s1 = base[h + 1];
    for (int i = s0 + tid; i < s1; i += 256)
        atomicAdd(&hist[bucketed[i].y & 255u], 1);
    __syncthreads();
    int n = h * 256 + tid;
    if (n < N) {
        int d = hist[tid];
        degInt[n] = d;
        dinv[n] = rsqrtf((float)d + 1.0f);
    }
}

// fused: per-bucket rowptr (block base = baseArr[h]) + edge scatter with
// pre-shifted src byte-offset and dinv[src] payload.
__global__ __launch_bounds__(256) void k_scancsc(const int* __restrict__ degInt,
                                                 const int* __restrict__ base,
                                                 const uint2* __restrict__ bucketed,
                                                 const float* __restrict__ dinv,
                                                 int* __restrict__ rowptr,
                                                 uint2* __restrict__ edata, int N) {
    __shared__ int s[256];
    __shared__ int cur[256];
    int h = blockIdx.x, tid = threadIdx.x;
    int i = h * 256 + tid;
    int d = (i < N) ? degInt[i] : 0;
    s[tid] = d;
    __syncthreads();
    for (int off = 1; off < 256; off <<= 1) {
        int t = (tid >= off) ? s[tid - off] : 0;
        __syncthreads();
        s[tid] += t;
        __syncthreads();
    }
    int incl = s[tid];
    int b = base[h];
    int rp = b + incl - d;
    if (i < N) {
        rowptr[i] = rp;
        if (i == N - 1) rowptr[N] = b + incl;
    }
    cur[tid] = rp;
    __syncthreads();
    int s0 = base[h], s1 = base[h + 1];
    for (int idx = s0 + tid; idx < s1; idx += 256) {
        uint2 e = bucketed[idx];
        int pos = atomicAdd(&cur[e.y & 255u], 1);
        edata[pos] = make_uint2(e.x << 8, __float_as_uint(dinv[e.x]));
    }
}

// ---------- fused W split (all 3 layers) ----------
__global__ void k_wsplit_all(const float* __restrict__ W1, uint* __restrict__ Wp1, int K0,
                             const float* __restrict__ W2, uint* __restrict__ Wp2,
                             const float* __restrict__ W3, uint* __restrict__ Wp3) {
    int t = blockIdx.x * 256 + threadIdx.x;
    int n1 = 128 * (K0 >> 1);
    int n2 = 128 * 64;           // K=128 layers
    const float* W; uint* Wp; int K; int loc;
    if (t < n1)                { W = W1; Wp = Wp1; K = K0;  loc = t; }
    else if (t < n1 + n2)      { W = W2; Wp = Wp2; K = 128; loc = t - n1; }
    else if (t < n1 + 2 * n2)  { W = W3; Wp = Wp3; K = 128; loc = t - n1 - n2; }
    else return;
    int half = K >> 1;
    int n = loc / half;
    int p = loc - n * half;
    uint hw, lw;
    splitPair(W[(2 * p) * HH + n], W[(2 * p + 1) * HH + n], hw, lw);
    Wp[n * K + 2 * p]     = hw;
    Wp[n * K + 2 * p + 1] = lw;
}

// ---------- MFMA GEMM (fp32 A, 3-term split): layer 1 ----------
template<int KT>   // K = KT*32
__global__ __launch_bounds__(256) void k_gemm_mfma(const float* __restrict__ A,
                                                   const uint* __restrict__ Wp,
                                                   ushort* __restrict__ out,
                                                   int N) {
    const int K = KT * 32;
    const int NCH = KT / 2;
    __shared__ uint Bs[128 * 68];
    int tid  = threadIdx.x;
    int wave = tid >> 6;
    int lane = tid & 63;
    int m16  = lane & 15;
    int quad = lane >> 4;
    int row  = blockIdx.x * 64 + wave * 16 + m16;
    int rowc = min(row, N - 1);

    const float4* a4 = (const float4*)(A + (size_t)rowc * K);
    float4 araw[2 * KT];
#pragma unroll
    for (int kt = 0; kt < KT; kt++) {
        araw[2 * kt]     = a4[kt * 8 + quad * 2];
        araw[2 * kt + 1] = a4[kt * 8 + quad * 2 + 1];
    }

    floatx4 acc[8];
#pragma unroll
    for (int c = 0; c < 8; c++) acc[c] = (floatx4){0.f, 0.f, 0.f, 0.f};

    int sn0 = tid >> 4;
    int sq4 = tid & 15;

    for (int ch = 0; ch < NCH; ch++) {
#pragma unroll
        for (int i = 0; i < 8; i++) {
            int n = i * 16 + sn0;
            *(uint4*)&Bs[n * 68 + sq4 * 4] =
                *(const uint4*)&Wp[(size_t)n * K + ch * 64 + sq4 * 4];
        }
        __syncthreads();

#pragma unroll
        for (int ktl = 0; ktl < 2; ktl++) {
            int ktg = ch * 2 + ktl;
            float4 f0 = araw[2 * ktg];
            float4 f1 = araw[2 * ktg + 1];
            uint ahw[4], alw[4];
            splitPair(f0.x, f0.y, ahw[0], alw[0]);
            splitPair(f0.z, f0.w, ahw[1], alw[1]);
            splitPair(f1.x, f1.y, ahw[2], alw[2]);
            splitPair(f1.z, f1.w, ahw[3], alw[3]);
            short8 a_hi = mk8(ahw[0], ahw[1], ahw[2], ahw[3]);
            short8 a_lo = mk8(alw[0], alw[1], alw[2], alw[3]);

#pragma unroll
            for (int c = 0; c < 8; c++) {
                const uint* bp = &Bs[(c * 16 + m16) * 68 + ktl * 32 + quad * 8];
                uint4 w0 = *(const uint4*)bp;
                uint4 w1 = *(const uint4*)(bp + 4);
                short8 b_hi = mk8(w0.x, w0.z, w1.x, w1.z);
                short8 b_lo = mk8(w0.y, w0.w, w1.y, w1.w);
                acc[c] = __builtin_amdgcn_mfma_f32_16x16x32_bf16(a_hi, b_hi, acc[c], 0, 0, 0);
                acc[c] = __builtin_amdgcn_mfma_f32_16x16x32_bf16(a_lo, b_hi, acc[c], 0, 0, 0);
                acc[c] = __builtin_amdgcn_mfma_f32_16x16x32_bf16(a_hi, b_lo, acc[c], 0, 0, 0);
            }
        }
        __syncthreads();
    }

    int rowbase = blockIdx.x * 64 + wave * 16 + quad * 4;
#pragma unroll
    for (int c = 0; c < 8; c++) {
#pragma unroll
        for (int r = 0; r < 4; r++) {
            int rr = rowbase + r;
            if (rr < N) out[(size_t)rr * HH + c * 16 + m16] = f2bf(acc[c][r]);
        }
    }
}

// ---------- MFMA GEMM (bf16 A, 2-term W-split): layers 2,3 ----------
template<int KT>
__global__ __launch_bounds__(256) void k_gemm_bf(const ushort* __restrict__ A,
                                                 const uint* __restrict__ Wp,
                                                 ushort* __restrict__ out,
                                                 int N) {
    const int K = KT * 32;
    const int NCH = KT / 2;
    __shared__ uint Bs[128 * 68];
    int tid  = threadIdx.x;
    int wave = tid >> 6;
    int lane = tid & 63;
    int m16  = lane & 15;
    int quad = lane >> 4;
    int row  = blockIdx.x * 64 + wave * 16 + m16;
    int rowc = min(row, N - 1);

    const uint4* a4 = (const uint4*)(A + (size_t)rowc * K);
    uint4 araw[KT];
#pragma unroll
    for (int kt = 0; kt < KT; kt++) araw[kt] = a4[kt * 4 + quad];

    floatx4 acc[8];
#pragma unroll
    for (int c = 0; c < 8; c++) acc[c] = (floatx4){0.f, 0.f, 0.f, 0.f};

    int sn0 = tid >> 4;
    int sq4 = tid & 15;

    for (int ch = 0; ch < NCH; ch++) {
#pragma unroll
        for (int i = 0; i < 8; i++) {
            int n = i * 16 + sn0;
            *(uint4*)&Bs[n * 68 + sq4 * 4] =
                *(const uint4*)&Wp[(size_t)n * K + ch * 64 + sq4 * 4];
        }
        __syncthreads();

#pragma unroll
        for (int ktl = 0; ktl < 2; ktl++) {
            uint4 av = araw[ch * 2 + ktl];
            short8 a = mk8(av.x, av.y, av.z, av.w);
#pragma unroll
            for (int c = 0; c < 8; c++) {
                const uint* bp = &Bs[(c * 16 + m16) * 68 + ktl * 32 + quad * 8];
                uint4 w0 = *(const uint4*)bp;
                uint4 w1 = *(const uint4*)(bp + 4);
                short8 b_hi = mk8(w0.x, w0.z, w1.x, w1.z);
                short8 b_lo = mk8(w0.y, w0.w, w1.y, w1.w);
                acc[c] = __builtin_amdgcn_mfma_f32_16x16x32_bf16(a, b_hi, acc[c], 0, 0, 0);
                acc[c] = __builtin_amdgcn_mfma_f32_16x16x32_bf16(a, b_lo, acc[c], 0, 0, 0);
            }
        }
        __syncthreads();
    }

    int rowbase = blockIdx.x * 64 + wave * 16 + quad * 4;
#pragma unroll
    for (int c = 0; c < 8; c++) {
#pragma unroll
        for (int r = 0; r < 4; r++) {
            int rr = rowbase + r;
            if (rr < N) out[(size_t)rr * HH + c * 16 + m16] = f2bf(acc[c][r]);
        }
    }
}

// ---------- CSR aggregation: 16 lanes/node, 4 nodes/wave, batch 32 ----------
__global__ __launch_bounds__(256) void k_agg(const ushort* __restrict__ xwb,
                                             const float* __restrict__ dinv,
                                             const int* __restrict__ rowptr,
                                             const uint2* __restrict__ edata,
                                             const float* __restrict__ b,
                                             const float* __restrict__ g,
                                             const float* __restrict__ beta,
                                             const float* __restrict__ m,
                                             const float* __restrict__ v,
                                             ushort* __restrict__ out,
                                             int N, int mode) {
    __shared__ uint  sS[512];
    __shared__ float sD[512];
    int wave = threadIdx.x >> 6;
    int lane = threadIdx.x & 63;
    int qq  = lane >> 4;
    int c16 = lane & 15;
    int n  = blockIdx.x * 16 + wave * 4 + qq;
    int nc = min(n, N - 1);
    int wb = wave * 128 + qq * 32;

    int beg = rowptr[nc];
    int end = rowptr[nc + 1];
    float di = dinv[nc];
    const char* xb = (const char*)xwb;
    uint coff = (uint)c16 << 4;

    float acc[8];
    {
        uint4 w = *(const uint4*)(xb + (((uint)nc << 8) | coff));
        acc[0] = di * bfLo(w.x); acc[1] = di * bfHi(w.x);
        acc[2] = di * bfLo(w.y); acc[3] = di * bfHi(w.y);
        acc[4] = di * bfLo(w.z); acc[5] = di * bfHi(w.z);
        acc[6] = di * bfLo(w.w); acc[7] = di * bfHi(w.w);
    }

    for (int b2 = beg; b2 < end; b2 += 32) {
        int cnt = min(32, end - b2);
        if (c16 < cnt) {
            uint2 e = edata[b2 + c16];
            sS[wb + c16] = e.x;                  // pre-shifted byte offset
            sD[wb + c16] = __uint_as_float(e.y);
        }
        int c2 = c16 + 16;
        if (c2 < cnt) {
            uint2 e = edata[b2 + c2];
            sS[wb + c2] = e.x;
            sD[wb + c2] = __uint_as_float(e.y);
        }
        // same-wave LDS write->read (lgkmcnt ordered); no barrier needed
#pragma unroll 4
        for (int j = 0; j < cnt; j++) {
            uint so  = sS[wb + j];
            float dj = sD[wb + j];
            uint4 w = *(const uint4*)(xb + (so | coff));
            acc[0] = fmaf(dj, bfLo(w.x), acc[0]);
            acc[1] = fmaf(dj, bfHi(w.x), acc[1]);
            acc[2] = fmaf(dj, bfLo(w.y), acc[2]);
            acc[3] = fmaf(dj, bfHi(w.y), acc[3]);
            acc[4] = fmaf(dj, bfLo(w.z), acc[4]);
            acc[5] = fmaf(dj, bfHi(w.z), acc[5]);
            acc[6] = fmaf(dj, bfLo(w.w), acc[6]);
            acc[7] = fmaf(dj, bfHi(w.w), acc[7]);
        }
    }

    int colb = c16 * 8;
    float4 b0 = *(const float4*)(b + colb);
    float4 b1 = *(const float4*)(b + colb + 4);
    float val[8];
    val[0] = di * acc[0] + b0.x; val[1] = di * acc[1] + b0.y;
    val[2] = di * acc[2] + b0.z; val[3] = di * acc[3] + b0.w;
    val[4] = di * acc[4] + b1.x; val[5] = di * acc[5] + b1.y;
    val[6] = di * acc[6] + b1.z; val[7] = di * acc[7] + b1.w;
    if (mode) {
#pragma unroll
        for (int half = 0; half < 2; half++) {
            float4 mm = *(const float4*)(m + colb + half * 4);
            float4 vv = *(const float4*)(v + colb + half * 4);
            float4 gg = *(const float4*)(g + colb + half * 4);
            float4 be = *(const float4*)(beta + colb + half * 4);
            int o = half * 4;
            val[o+0] = fmaxf((val[o+0] - mm.x) * rsqrtf(vv.x + BN_EPS) * gg.x + be.x, 0.f);
            val[o+1] = fmaxf((val[o+1] - mm.y) * rsqrtf(vv.y + BN_EPS) * gg.y + be.y, 0.f);
            val[o+2] = fmaxf((val[o+2] - mm.z) * rsqrtf(vv.z + BN_EPS) * gg.z + be.z, 0.f);
            val[o+3] = fmaxf((val[o+3] - mm.w) * rsqrtf(vv.w + BN_EPS) * gg.w + be.w, 0.f);
        }
    }
    if (n < N) {
        uint4 o;
        o.x = packbf(val[0], val[1]);
        o.y = packbf(val[2], val[3]);
        o.z = packbf(val[4], val[5]);
        o.w = packbf(val[6], val[7]);
        *(uint4*)((char*)out + (((uint)n << 8) | coff)) = o;
    }
}

// ---------- fused mean-pool + classifier: one block per graph ----------
// batch is sorted: binary-search graph bounds; 256 thr = 128 cols x 2 row-halves.
__global__ __launch_bounds__(256) void k_poolcls(const ushort* __restrict__ h,
                                                 const int* __restrict__ batch,
                                                 const float* __restrict__ Wc1,
                                                 const float* __restrict__ bc1,
                                                 const float* __restrict__ Wc2,
                                                 const float* __restrict__ bc2,
                                                 float* __restrict__ out,
                                                 int N, int Hc, int C) {
    __shared__ float red[256];
    __shared__ float pooled[HH];
    __shared__ float z[HH];
    __shared__ int bounds[2];
    int g = blockIdx.x, tid = threadIdx.x;
    if (tid < 2) {
        int target = g + tid;
        int lo = 0, hi = N;
        while (lo < hi) {
            int mid = (lo + hi) >> 1;
            if (batch[mid] < target) lo = mid + 1; else hi = mid;
        }
        bounds[tid] = lo;
    }
    __syncthreads();
    int s0 = bounds[0], s1 = bounds[1];
    int col = tid & 127, half = tid >> 7;
    float acc = 0.0f;
    for (int n = s0 + half; n < s1; n += 2)
        acc += __uint_as_float(((uint)h[(size_t)n * HH + col]) << 16);
    red[tid] = acc;
    __syncthreads();
    float cnt = fmaxf((float)(s1 - s0), 1.0f);
    if (tid < HH) pooled[tid] = (red[tid] + red[tid + 128]) / cnt;
    __syncthreads();
    if (tid < Hc) {
        float a = bc1[tid];
        for (int k = 0; k < HH; k++) a += pooled[k] * Wc1[k * Hc + tid];
        z[tid] = fmaxf(a, 0.0f);
    }
    __syncthreads();
    if (tid < C) {
        float a = bc2[tid];
        for (int k = 0; k < Hc; k++) a += z[k] * Wc2[k * C + tid];
        out[(size_t)g * C + tid] = a;
    }
}

extern "C" void kernel_launch(void* const* d_in, const int* in_sizes, int n_in,
                              void* d_out, int out_size, void* d_ws, size_t ws_size,
                              hipStream_t stream) {
    const float* x     = (const float*)d_in[0];
    const int*   ei    = (const int*)d_in[1];
    const int*   batch = (const int*)d_in[2];
    const float* W1    = (const float*)d_in[3];
    const float* b1    = (const float*)d_in[4];
    const float* W2    = (const float*)d_in[5];
    const float* b2    = (const float*)d_in[6];
    const float* W3    = (const float*)d_in[7];
    const float* b3    = (const float*)d_in[8];
    const float* bn1_g = (const float*)d_in[9];
    const float* bn1_b = (const float*)d_in[10];
    const float* bn1_m = (const float*)d_in[11];
    const float* bn1_v = (const float*)d_in[12];
    const float* bn2_g = (const float*)d_in[13];
    const float* bn2_b = (const float*)d_in[14];
    const float* bn2_m = (const float*)d_in[15];
    const float* bn2_v = (const float*)d_in[16];
    const float* Wc1   = (const float*)d_in[17];
    const float* bc1   = (const float*)d_in[18];
    const float* Wc2   = (const float*)d_in[19];
    const float* bc2   = (const float*)d_in[20];
    float* out = (float*)d_out;

    const int N  = in_sizes[2];
    const int E  = in_sizes[1] / 2;
    const int K0 = in_sizes[0] / N;      // 256
    const int Hc = in_sizes[18];         // 64
    const int C  = in_sizes[20];         // 16
    const int G  = out_size / C;         // 64

    const int* srcv = ei;
    const int* dstv = ei + E;

    // workspace layout
    float* ws = (float*)d_ws;
    size_t NH = (size_t)N * HH;
    size_t Na = (((size_t)N + 255) / 256) * 256;
    size_t Ea = (((size_t)E + 255) / 256) * 256;
    ushort* bufA   = (ushort*)ws;            // N*128 bf16
    ushort* bufB   = (ushort*)(ws + NH);     // N*128 bf16
    float* dinv    = ws + 2 * NH;
    int*   degInt  = (int*)(dinv + Na);
    int*   rowptr  = degInt + Na;
    uint2* edata   = (uint2*)(rowptr + Na + 256);  // E * 8B
    uint2* bucketed= edata + Ea;                   // E * 8B
    int*   gH      = (int*)(bucketed + Ea);
    int*   gC      = gH + 65536;
    int*   totals  = gC + 65536;
    int*   baseArr = totals + 256;                 // 257 (pad 512)
    uint*  Wp1     = (uint*)(baseArr + 512);
    uint*  Wp2     = Wp1 + (size_t)K0 * HH;
    uint*  Wp3     = Wp2 + (size_t)HH * HH;

    int tile = (E + 255) / 256;
    int gGemm = (N + 63) / 64;
    int gAgg  = (N + 15) / 16;
    int nws   = 128 * (K0 / 2) + 2 * 128 * 64;

    // ---- CSR build (6 kernels, no global atomics) ----
    k_ahist<<<256, 256, 0, stream>>>(dstv, gH, E, tile);
    k_scan1<<<256, 256, 0, stream>>>(gH, gC, totals);
    k_scan2<<<1, 256, 0, stream>>>(totals, baseArr);
    k_asc<<<256, 256, 0, stream>>>(srcv, dstv, gC, baseArr, bucketed, E, tile);
    k_bdeg<<<256, 256, 0, stream>>>(bucketed, baseArr, degInt, dinv, N);
    k_scancsc<<<256, 256, 0, stream>>>(degInt, baseArr, bucketed, dinv,
                                       rowptr, edata, N);

    // ---- weight splits (1 kernel) ----
    k_wsplit_all<<<(nws + 255) / 256, 256, 0, stream>>>(W1, Wp1, K0, W2, Wp2, W3, Wp3);

    // ---- layer 1 (fp32 A, 3-term) ----
    if (K0 == 256)
        k_gemm_mfma<8><<<gGemm, 256, 0, stream>>>(x, Wp1, bufA, N);
    else
        k_gemm_mfma<4><<<gGemm, 256, 0, stream>>>(x, Wp1, bufA, N);
    k_agg<<<gAgg, 256, 0, stream>>>(bufA, dinv, rowptr, edata, b1,
                                    bn1_g, bn1_b, bn1_m, bn1_v, bufB, N, 1);
    // ---- layer 2 (bf16 A, 2-term) ----
    k_gemm_bf<4><<<gGemm, 256, 0, stream>>>(bufB, Wp2, bufA, N);
    k_agg<<<gAgg, 256, 0, stream>>>(bufA, dinv, rowptr, edata, b2,
                                    bn2_g, bn2_b, bn2_m, bn2_v, bufB, N, 1);
    // ---- layer 3 (bf16 A, 2-term) ----
    k_gemm_bf<4><<<gGemm, 256, 0, stream>>>(bufB, Wp3, bufA, N);
    k_agg<<<gAgg, 256, 0, stream>>>(bufA, dinv, rowptr, edata, b3,
                                    nullptr, nullptr, nullptr, nullptr, bufB, N, 0);

    // ---- fused pool + classifier ----
    k_poolcls<<<G, 256, 0, stream>>>(bufB, batch, Wc1, bc1, Wc2, bc2, out, N, Hc, C);
}

// Round 12
// 320.433 us; speedup vs baseline: 1.2708x; 1.2708x over previous
//
#include <hip/hip_runtime.h>

#define HH 128
#define BN_EPS 1e-5f

typedef __attribute__((ext_vector_type(8))) short short8;
typedef __attribute__((ext_vector_type(4))) float floatx4;

__device__ inline short8 mk8(uint a, uint b, uint c, uint d) {
    union { uint u[4]; short8 s; } t;
    t.u[0] = a; t.u[1] = b; t.u[2] = c; t.u[3] = d;
    return t.s;
}

__device__ inline ushort f2bf(float f) {
    uint u = __float_as_uint(f);
    u = u + 0x7FFFu + ((u >> 16) & 1u);
    return (ushort)(u >> 16);
}

__device__ inline uint packbf(float lo, float hi) {
    return ((uint)f2bf(hi) << 16) | (uint)f2bf(lo);
}

__device__ inline float bfLo(uint u) { return __uint_as_float(u << 16); }
__device__ inline float bfHi(uint u) { return __uint_as_float(u & 0xFFFF0000u); }

__device__ inline void splitPair(float f0, float f1, uint& hw, uint& lw) {
    uint u0 = __float_as_uint(f0), u1 = __float_as_uint(f1);
    hw = __builtin_amdgcn_perm(u1, u0, 0x07060302);
    float r0 = f0 - __uint_as_float(u0 & 0xFFFF0000u);
    float r1 = f1 - __uint_as_float(u1 & 0xFFFF0000u);
    lw = __builtin_amdgcn_perm(__float_as_uint(r1), __float_as_uint(r0), 0x07060302);
}

// ================= CSR build via 2-level bucket sort (NO global atomics) ====
// bucket h = dst>>8 covers exactly nodes [h*256, h*256+256) -> bucket totals
// double as the rowptr block bases.

__global__ __launch_bounds__(256) void k_ahist(const int* __restrict__ dst,
                                               int* __restrict__ gH, int E, int tile) {
    __shared__ int hist[256];
    int b = blockIdx.x, tid = threadIdx.x;
    hist[tid] = 0;
    __syncthreads();
    int s0 = b * tile, s1 = min(s0 + tile, E);
    for (int i = s0 + tid; i < s1; i += 256)
        atomicAdd(&hist[((unsigned)dst[i]) >> 8], 1);
    __syncthreads();
    gH[tid * 256 + b] = hist[tid];
}

__global__ __launch_bounds__(256) void k_scan1(const int* __restrict__ gH,
                                               int* __restrict__ gC,
                                               int* __restrict__ totals) {
    __shared__ int s[256];
    int h = blockIdx.x, b = threadIdx.x;
    int v = gH[h * 256 + b];
    s[b] = v;
    __syncthreads();
    for (int off = 1; off < 256; off <<= 1) {
        int t = (b >= off) ? s[b - off] : 0;
        __syncthreads();
        s[b] += t;
        __syncthreads();
    }
    gC[h * 256 + b] = s[b] - v;
    if (b == 255) totals[h] = s[255];
}

__global__ __launch_bounds__(256) void k_scan2(const int* __restrict__ totals,
                                               int* __restrict__ base) {
    __shared__ int s[256];
    int tid = threadIdx.x;
    int v = totals[tid];
    s[tid] = v;
    __syncthreads();
    for (int off = 1; off < 256; off <<= 1) {
        int t = (tid >= off) ? s[tid - off] : 0;
        __syncthreads();
        s[tid] += t;
        __syncthreads();
    }
    base[tid] = s[tid] - v;
    if (tid == 255) base[256] = s[255];
}

__global__ __launch_bounds__(256) void k_asc(const int* __restrict__ src,
                                             const int* __restrict__ dst,
                                             const int* __restrict__ gC,
                                             const int* __restrict__ base,
                                             uint2* __restrict__ bucketed,
                                             int E, int tile) {
    __shared__ int cur[256];
    int b = blockIdx.x, tid = threadIdx.x;
    cur[tid] = gC[tid * 256 + b] + base[tid];
    __syncthreads();
    int s0 = b * tile, s1 = min(s0 + tile, E);
    for (int i = s0 + tid; i < s1; i += 256) {
        int d = dst[i];
        int pos = atomicAdd(&cur[((unsigned)d) >> 8], 1);
        bucketed[pos] = make_uint2((uint)src[i], (uint)d);
    }
}

__global__ __launch_bounds__(256) void k_bdeg(const uint2* __restrict__ bucketed,
                                              const int* __restrict__ base,
                                              int* __restrict__ degInt,
                                              float* __restrict__ dinv, int N) {
    __shared__ int hist[256];
    int h = blockIdx.x, tid = threadIdx.x;
    hist[tid] = 0;
    __syncthreads();
    int s0 = base[h], s1 = base[h + 1];
    for (int i = s0 + tid; i < s1; i += 256)
        atomicAdd(&hist[bucketed[i].y & 255u], 1);
    __syncthreads();
    int n = h * 256 + tid;
    if (n < N) {
        int d = hist[tid];
        degInt[n] = d;
        dinv[n] = rsqrtf((float)d + 1.0f);
    }
}

__global__ __launch_bounds__(256) void k_scancsc(const int* __restrict__ degInt,
                                                 const int* __restrict__ base,
                                                 const uint2* __restrict__ bucketed,
                                                 const float* __restrict__ dinv,
                                                 int* __restrict__ rowptr,
                                                 uint2* __restrict__ edata, int N) {
    __shared__ int s[256];
    __shared__ int cur[256];
    int h = blockIdx.x, tid = threadIdx.x;
    int i = h * 256 + tid;
    int d = (i < N) ? degInt[i] : 0;
    s[tid] = d;
    __syncthreads();
    for (int off = 1; off < 256; off <<= 1) {
        int t = (tid >= off) ? s[tid - off] : 0;
        __syncthreads();
        s[tid] += t;
        __syncthreads();
    }
    int incl = s[tid];
    int b = base[h];
    int rp = b + incl - d;
    if (i < N) {
        rowptr[i] = rp;
        if (i == N - 1) rowptr[N] = b + incl;
    }
    cur[tid] = rp;
    __syncthreads();
    int s0 = base[h], s1 = base[h + 1];
    for (int idx = s0 + tid; idx < s1; idx += 256) {
        uint2 e = bucketed[idx];
        int pos = atomicAdd(&cur[e.y & 255u], 1);
        edata[pos] = make_uint2(e.x << 8, __float_as_uint(dinv[e.x]));
    }
}

// ---------- fused W split (all 3 layers) ----------
__global__ void k_wsplit_all(const float* __restrict__ W1, uint* __restrict__ Wp1, int K0,
                             const float* __restrict__ W2, uint* __restrict__ Wp2,
                             const float* __restrict__ W3, uint* __restrict__ Wp3) {
    int t = blockIdx.x * 256 + threadIdx.x;
    int n1 = 128 * (K0 >> 1);
    int n2 = 128 * 64;           // K=128 layers
    const float* W; uint* Wp; int K; int loc;
    if (t < n1)                { W = W1; Wp = Wp1; K = K0;  loc = t; }
    else if (t < n1 + n2)      { W = W2; Wp = Wp2; K = 128; loc = t - n1; }
    else if (t < n1 + 2 * n2)  { W = W3; Wp = Wp3; K = 128; loc = t - n1 - n2; }
    else return;
    int half = K >> 1;
    int n = loc / half;
    int p = loc - n * half;
    uint hw, lw;
    splitPair(W[(2 * p) * HH + n], W[(2 * p + 1) * HH + n], hw, lw);
    Wp[n * K + 2 * p]     = hw;
    Wp[n * K + 2 * p + 1] = lw;
}

// ---------- MFMA GEMM (fp32 A, 3-term split): layer 1 ----------
template<int KT>   // K = KT*32
__global__ __launch_bounds__(256) void k_gemm_mfma(const float* __restrict__ A,
                                                   const uint* __restrict__ Wp,
                                                   ushort* __restrict__ out,
                                                   int N) {
    const int K = KT * 32;
    const int NCH = KT / 2;
    __shared__ uint Bs[128 * 68];
    int tid  = threadIdx.x;
    int wave = tid >> 6;
    int lane = tid & 63;
    int m16  = lane & 15;
    int quad = lane >> 4;
    int row  = blockIdx.x * 64 + wave * 16 + m16;
    int rowc = min(row, N - 1);

    const float4* a4 = (const float4*)(A + (size_t)rowc * K);
    float4 araw[2 * KT];
#pragma unroll
    for (int kt = 0; kt < KT; kt++) {
        araw[2 * kt]     = a4[kt * 8 + quad * 2];
        araw[2 * kt + 1] = a4[kt * 8 + quad * 2 + 1];
    }

    floatx4 acc[8];
#pragma unroll
    for (int c = 0; c < 8; c++) acc[c] = (floatx4){0.f, 0.f, 0.f, 0.f};

    int sn0 = tid >> 4;
    int sq4 = tid & 15;

    for (int ch = 0; ch < NCH; ch++) {
#pragma unroll
        for (int i = 0; i < 8; i++) {
            int n = i * 16 + sn0;
            *(uint4*)&Bs[n * 68 + sq4 * 4] =
                *(const uint4*)&Wp[(size_t)n * K + ch * 64 + sq4 * 4];
        }
        __syncthreads();

#pragma unroll
        for (int ktl = 0; ktl < 2; ktl++) {
            int ktg = ch * 2 + ktl;
            float4 f0 = araw[2 * ktg];
            float4 f1 = araw[2 * ktg + 1];
            uint ahw[4], alw[4];
            splitPair(f0.x, f0.y, ahw[0], alw[0]);
            splitPair(f0.z, f0.w, ahw[1], alw[1]);
            splitPair(f1.x, f1.y, ahw[2], alw[2]);
            splitPair(f1.z, f1.w, ahw[3], alw[3]);
            short8 a_hi = mk8(ahw[0], ahw[1], ahw[2], ahw[3]);
            short8 a_lo = mk8(alw[0], alw[1], alw[2], alw[3]);

#pragma unroll
            for (int c = 0; c < 8; c++) {
                const uint* bp = &Bs[(c * 16 + m16) * 68 + ktl * 32 + quad * 8];
                uint4 w0 = *(const uint4*)bp;
                uint4 w1 = *(const uint4*)(bp + 4);
                short8 b_hi = mk8(w0.x, w0.z, w1.x, w1.z);
                short8 b_lo = mk8(w0.y, w0.w, w1.y, w1.w);
                acc[c] = __builtin_amdgcn_mfma_f32_16x16x32_bf16(a_hi, b_hi, acc[c], 0, 0, 0);
                acc[c] = __builtin_amdgcn_mfma_f32_16x16x32_bf16(a_lo, b_hi, acc[c], 0, 0, 0);
                acc[c] = __builtin_amdgcn_mfma_f32_16x16x32_bf16(a_hi, b_lo, acc[c], 0, 0, 0);
            }
        }
        __syncthreads();
    }

    int rowbase = blockIdx.x * 64 + wave * 16 + quad * 4;
#pragma unroll
    for (int c = 0; c < 8; c++) {
#pragma unroll
        for (int r = 0; r < 4; r++) {
            int rr = rowbase + r;
            if (rr < N) out[(size_t)rr * HH + c * 16 + m16] = f2bf(acc[c][r]);
        }
    }
}

// ---------- MFMA GEMM (bf16 A, 2-term W-split): layers 2,3 ----------
template<int KT>
__global__ __launch_bounds__(256) void k_gemm_bf(const ushort* __restrict__ A,
                                                 const uint* __restrict__ Wp,
                                                 ushort* __restrict__ out,
                                                 int N) {
    const int K = KT * 32;
    const int NCH = KT / 2;
    __shared__ uint Bs[128 * 68];
    int tid  = threadIdx.x;
    int wave = tid >> 6;
    int lane = tid & 63;
    int m16  = lane & 15;
    int quad = lane >> 4;
    int row  = blockIdx.x * 64 + wave * 16 + m16;
    int rowc = min(row, N - 1);

    const uint4* a4 = (const uint4*)(A + (size_t)rowc * K);
    uint4 araw[KT];
#pragma unroll
    for (int kt = 0; kt < KT; kt++) araw[kt] = a4[kt * 4 + quad];

    floatx4 acc[8];
#pragma unroll
    for (int c = 0; c < 8; c++) acc[c] = (floatx4){0.f, 0.f, 0.f, 0.f};

    int sn0 = tid >> 4;
    int sq4 = tid & 15;

    for (int ch = 0; ch < NCH; ch++) {
#pragma unroll
        for (int i = 0; i < 8; i++) {
            int n = i * 16 + sn0;
            *(uint4*)&Bs[n * 68 + sq4 * 4] =
                *(const uint4*)&Wp[(size_t)n * K + ch * 64 + sq4 * 4];
        }
        __syncthreads();

#pragma unroll
        for (int ktl = 0; ktl < 2; ktl++) {
            uint4 av = araw[ch * 2 + ktl];
            short8 a = mk8(av.x, av.y, av.z, av.w);
#pragma unroll
            for (int c = 0; c < 8; c++) {
                const uint* bp = &Bs[(c * 16 + m16) * 68 + ktl * 32 + quad * 8];
                uint4 w0 = *(const uint4*)bp;
                uint4 w1 = *(const uint4*)(bp + 4);
                short8 b_hi = mk8(w0.x, w0.z, w1.x, w1.z);
                short8 b_lo = mk8(w0.y, w0.w, w1.y, w1.w);
                acc[c] = __builtin_amdgcn_mfma_f32_16x16x32_bf16(a, b_hi, acc[c], 0, 0, 0);
                acc[c] = __builtin_amdgcn_mfma_f32_16x16x32_bf16(a, b_lo, acc[c], 0, 0, 0);
            }
        }
        __syncthreads();
    }

    int rowbase = blockIdx.x * 64 + wave * 16 + quad * 4;
#pragma unroll
    for (int c = 0; c < 8; c++) {
#pragma unroll
        for (int r = 0; r < 4; r++) {
            int rr = rowbase + r;
            if (rr < N) out[(size_t)rr * HH + c * 16 + m16] = f2bf(acc[c][r]);
        }
    }
}

// ---------- CSR aggregation: 16 lanes/node, 4 nodes/wave, batch 32 ----------
__global__ __launch_bounds__(256) void k_agg(const ushort* __restrict__ xwb,
                                             const float* __restrict__ dinv,
                                             const int* __restrict__ rowptr,
                                             const uint2* __restrict__ edata,
                                             const float* __restrict__ b,
                                             const float* __restrict__ g,
                                             const float* __restrict__ beta,
                                             const float* __restrict__ m,
                                             const float* __restrict__ v,
                                             ushort* __restrict__ out,
                                             int N, int mode) {
    __shared__ uint  sS[512];
    __shared__ float sD[512];
    int wave = threadIdx.x >> 6;
    int lane = threadIdx.x & 63;
    int qq  = lane >> 4;
    int c16 = lane & 15;
    int n  = blockIdx.x * 16 + wave * 4 + qq;
    int nc = min(n, N - 1);
    int wb = wave * 128 + qq * 32;

    int beg = rowptr[nc];
    int end = rowptr[nc + 1];
    float di = dinv[nc];
    const char* xb = (const char*)xwb;
    uint coff = (uint)c16 << 4;

    float acc[8];
    {
        uint4 w = *(const uint4*)(xb + (((uint)nc << 8) | coff));
        acc[0] = di * bfLo(w.x); acc[1] = di * bfHi(w.x);
        acc[2] = di * bfLo(w.y); acc[3] = di * bfHi(w.y);
        acc[4] = di * bfLo(w.z); acc[5] = di * bfHi(w.z);
        acc[6] = di * bfLo(w.w); acc[7] = di * bfHi(w.w);
    }

    for (int b2 = beg; b2 < end; b2 += 32) {
        int cnt = min(32, end - b2);
        if (c16 < cnt) {
            uint2 e = edata[b2 + c16];
            sS[wb + c16] = e.x;
            sD[wb + c16] = __uint_as_float(e.y);
        }
        int c2 = c16 + 16;
        if (c2 < cnt) {
            uint2 e = edata[b2 + c2];
            sS[wb + c2] = e.x;
            sD[wb + c2] = __uint_as_float(e.y);
        }
        // same-wave LDS write->read (lgkmcnt ordered); no barrier needed
#pragma unroll 4
        for (int j = 0; j < cnt; j++) {
            uint so  = sS[wb + j];
            float dj = sD[wb + j];
            uint4 w = *(const uint4*)(xb + (so | coff));
            acc[0] = fmaf(dj, bfLo(w.x), acc[0]);
            acc[1] = fmaf(dj, bfHi(w.x), acc[1]);
            acc[2] = fmaf(dj, bfLo(w.y), acc[2]);
            acc[3] = fmaf(dj, bfHi(w.y), acc[3]);
            acc[4] = fmaf(dj, bfLo(w.z), acc[4]);
            acc[5] = fmaf(dj, bfHi(w.z), acc[5]);
            acc[6] = fmaf(dj, bfLo(w.w), acc[6]);
            acc[7] = fmaf(dj, bfHi(w.w), acc[7]);
        }
    }

    int colb = c16 * 8;
    float4 b0 = *(const float4*)(b + colb);
    float4 b1 = *(const float4*)(b + colb + 4);
    float val[8];
    val[0] = di * acc[0] + b0.x; val[1] = di * acc[1] + b0.y;
    val[2] = di * acc[2] + b0.z; val[3] = di * acc[3] + b0.w;
    val[4] = di * acc[4] + b1.x; val[5] = di * acc[5] + b1.y;
    val[6] = di * acc[6] + b1.z; val[7] = di * acc[7] + b1.w;
    if (mode) {
#pragma unroll
        for (int half = 0; half < 2; half++) {
            float4 mm = *(const float4*)(m + colb + half * 4);
            float4 vv = *(const float4*)(v + colb + half * 4);
            float4 gg = *(const float4*)(g + colb + half * 4);
            float4 be = *(const float4*)(beta + colb + half * 4);
            int o = half * 4;
            val[o+0] = fmaxf((val[o+0] - mm.x) * rsqrtf(vv.x + BN_EPS) * gg.x + be.x, 0.f);
            val[o+1] = fmaxf((val[o+1] - mm.y) * rsqrtf(vv.y + BN_EPS) * gg.y + be.y, 0.f);
            val[o+2] = fmaxf((val[o+2] - mm.z) * rsqrtf(vv.z + BN_EPS) * gg.z + be.z, 0.f);
            val[o+3] = fmaxf((val[o+3] - mm.w) * rsqrtf(vv.w + BN_EPS) * gg.w + be.w, 0.f);
        }
    }
    if (n < N) {
        uint4 o;
        o.x = packbf(val[0], val[1]);
        o.y = packbf(val[2], val[3]);
        o.z = packbf(val[4], val[5]);
        o.w = packbf(val[6], val[7]);
        *(uint4*)((char*)out + (((uint)n << 8) | coff)) = o;
    }
}

// ---------- fused mean-pool + classifier: one block per graph ----------
// thread = (c16 = 8-col group, r = 16-row phase) -> uint4 loads, 16 rows in
// flight per iteration; 16-phase LDS tree reduction; then tiny MLP.
__global__ __launch_bounds__(256) void k_poolcls(const ushort* __restrict__ h,
                                                 const int* __restrict__ batch,
                                                 const float* __restrict__ Wc1,
                                                 const float* __restrict__ bc1,
                                                 const float* __restrict__ Wc2,
                                                 const float* __restrict__ bc2,
                                                 float* __restrict__ out,
                                                 int N, int Hc, int C) {
    __shared__ float red[16 * 128];   // 8 KB
    __shared__ float pooled[HH];
    __shared__ float z[HH];
    __shared__ int bounds[2];
    int g = blockIdx.x, tid = threadIdx.x;
    if (tid < 2) {
        int target = g + tid;
        int lo = 0, hi = N;
        while (lo < hi) {
            int mid = (lo + hi) >> 1;
            if (batch[mid] < target) lo = mid + 1; else hi = mid;
        }
        bounds[tid] = lo;
    }
    __syncthreads();
    int s0 = bounds[0], s1 = bounds[1];
    int c16 = tid & 15;
    int r   = tid >> 4;
    const char* hb = (const char*)h;
    uint coff = (uint)c16 << 4;
    float acc[8];
#pragma unroll
    for (int i = 0; i < 8; i++) acc[i] = 0.0f;
    for (int n = s0 + r; n < s1; n += 16) {
        uint4 w = *(const uint4*)(hb + (((uint)n << 8) | coff));
        acc[0] += bfLo(w.x); acc[1] += bfHi(w.x);
        acc[2] += bfLo(w.y); acc[3] += bfHi(w.y);
        acc[4] += bfLo(w.z); acc[5] += bfHi(w.z);
        acc[6] += bfLo(w.w); acc[7] += bfHi(w.w);
    }
#pragma unroll
    for (int i = 0; i < 8; i++) red[r * 128 + c16 * 8 + i] = acc[i];
    __syncthreads();
    for (int off = 8; off > 0; off >>= 1) {
        if (r < off) {
#pragma unroll
            for (int i = 0; i < 8; i++)
                red[r * 128 + c16 * 8 + i] += red[(r + off) * 128 + c16 * 8 + i];
        }
        __syncthreads();
    }
    float cnt = fmaxf((float)(s1 - s0), 1.0f);
    if (tid < HH) pooled[tid] = red[tid] / cnt;
    __syncthreads();
    if (tid < Hc) {
        float a = bc1[tid];
        for (int k = 0; k < HH; k++) a += pooled[k] * Wc1[k * Hc + tid];
        z[tid] = fmaxf(a, 0.0f);
    }
    __syncthreads();
    if (tid < C) {
        float a = bc2[tid];
        for (int k = 0; k < Hc; k++) a += z[k] * Wc2[k * C + tid];
        out[(size_t)g * C + tid] = a;
    }
}

extern "C" void kernel_launch(void* const* d_in, const int* in_sizes, int n_in,
                              void* d_out, int out_size, void* d_ws, size_t ws_size,
                              hipStream_t stream) {
    const float* x     = (const float*)d_in[0];
    const int*   ei    = (const int*)d_in[1];
    const int*   batch = (const int*)d_in[2];
    const float* W1    = (const float*)d_in[3];
    const float* b1    = (const float*)d_in[4];
    const float* W2    = (const float*)d_in[5];
    const float* b2    = (const float*)d_in[6];
    const float* W3    = (const float*)d_in[7];
    const float* b3    = (const float*)d_in[8];
    const float* bn1_g = (const float*)d_in[9];
    const float* bn1_b = (const float*)d_in[10];
    const float* bn1_m = (const float*)d_in[11];
    const float* bn1_v = (const float*)d_in[12];
    const float* bn2_g = (const float*)d_in[13];
    const float* bn2_b = (const float*)d_in[14];
    const float* bn2_m = (const float*)d_in[15];
    const float* bn2_v = (const float*)d_in[16];
    const float* Wc1   = (const float*)d_in[17];
    const float* bc1   = (const float*)d_in[18];
    const float* Wc2   = (const float*)d_in[19];
    const float* bc2   = (const float*)d_in[20];
    float* out = (float*)d_out;

    const int N  = in_sizes[2];
    const int E  = in_sizes[1] / 2;
    const int K0 = in_sizes[0] / N;      // 256
    const int Hc = in_sizes[18];         // 64
    const int C  = in_sizes[20];         // 16
    const int G  = out_size / C;         // 64

    const int* srcv = ei;
    const int* dstv = ei + E;

    // workspace layout
    float* ws = (float*)d_ws;
    size_t NH = (size_t)N * HH;
    size_t Na = (((size_t)N + 255) / 256) * 256;
    size_t Ea = (((size_t)E + 255) / 256) * 256;
    ushort* bufA   = (ushort*)ws;            // N*128 bf16
    ushort* bufB   = (ushort*)(ws + NH);     // N*128 bf16
    float* dinv    = ws + 2 * NH;
    int*   degInt  = (int*)(dinv + Na);
    int*   rowptr  = degInt + Na;
    uint2* edata   = (uint2*)(rowptr + Na + 256);  // E * 8B
    uint2* bucketed= edata + Ea;                   // E * 8B
    int*   gH      = (int*)(bucketed + Ea);
    int*   gC      = gH + 65536;
    int*   totals  = gC + 65536;
    int*   baseArr = totals + 256;                 // 257 (pad 512)
    uint*  Wp1     = (uint*)(baseArr + 512);
    uint*  Wp2     = Wp1 + (size_t)K0 * HH;
    uint*  Wp3     = Wp2 + (size_t)HH * HH;

    int tile = (E + 255) / 256;
    int gGemm = (N + 63) / 64;
    int gAgg  = (N + 15) / 16;
    int nws   = 128 * (K0 / 2) + 2 * 128 * 64;

    // ---- CSR build (6 kernels, no global atomics) ----
    k_ahist<<<256, 256, 0, stream>>>(dstv, gH, E, tile);
    k_scan1<<<256, 256, 0, stream>>>(gH, gC, totals);
    k_scan2<<<1, 256, 0, stream>>>(totals, baseArr);
    k_asc<<<256, 256, 0, stream>>>(srcv, dstv, gC, baseArr, bucketed, E, tile);
    k_bdeg<<<256, 256, 0, stream>>>(bucketed, baseArr, degInt, dinv, N);
    k_scancsc<<<256, 256, 0, stream>>>(degInt, baseArr, bucketed, dinv,
                                       rowptr, edata, N);

    // ---- weight splits (1 kernel) ----
    k_wsplit_all<<<(nws + 255) / 256, 256, 0, stream>>>(W1, Wp1, K0, W2, Wp2, W3, Wp3);

    // ---- layer 1 (fp32 A, 3-term) ----
    if (K0 == 256)
        k_gemm_mfma<8><<<gGemm, 256, 0, stream>>>(x, Wp1, bufA, N);
    else
        k_gemm_mfma<4><<<gGemm, 256, 0, stream>>>(x, Wp1, bufA, N);
    k_agg<<<gAgg, 256, 0, stream>>>(bufA, dinv, rowptr, edata, b1,
                                    bn1_g, bn1_b, bn1_m, bn1_v, bufB, N, 1);
    // ---- layer 2 (bf16 A, 2-term) ----
    k_gemm_bf<4><<<gGemm, 256, 0, stream>>>(bufB, Wp2, bufA, N);
    k_agg<<<gAgg, 256, 0, stream>>>(bufA, dinv, rowptr, edata, b2,
                                    bn2_g, bn2_b, bn2_m, bn2_v, bufB, N, 1);
    // ---- layer 3 (bf16 A, 2-term) ----
    k_gemm_bf<4><<<gGemm, 256, 0, stream>>>(bufB, Wp3, bufA, N);
    k_agg<<<gAgg, 256, 0, stream>>>(bufA, dinv, rowptr, edata, b3,
                                    nullptr, nullptr, nullptr, nullptr, bufB, N, 0);

    // ---- fused pool + classifier ----
    k_poolcls<<<G, 256, 0, stream>>>(bufB, batch, Wc1, bc1, Wc2, bc2, out, N, Hc, C);
}